// Round 5
// baseline (319.122 us; speedup 1.0000x reference)
//
#include <hip/hip_runtime.h>
#include <hip/hip_cooperative_groups.h>

namespace cg = cooperative_groups;

// Round 5: single cooperative kernel. R4's main loop verbatim (lane-per-row,
// 48B loads, unroll x2 unconditional) -> per-block partial in d_ws ->
// grid.sync() -> block 0 reduces partials and writes d_out. Removes the
// ~3.8us second-dispatch + graph-gap overhead. 268 MB mandatory traffic.

__device__ __forceinline__ float row_term(const float4* __restrict__ O4,
                                          const float4* __restrict__ L4,
                                          int r) {
    const int b4 = r * 4;                       // first float4 of row r
    float4 l0 = L4[b4 + 0];
    float4 l1 = L4[b4 + 1];
    float4 l2 = L4[b4 + 2];
    float4 o0 = O4[b4 + 0];
    float4 o1 = O4[b4 + 1];
    float4 o2 = O4[b4 + 2];

    const float lab0 = l0.x;
    const int rr = (int)rintf(3.0f * lab0);     // round-half-even = jnp.round
    int n; float inv;
    if (lab0 == 0.0f) { n = 1; inv = 1.0f; }
    else if (rr == 1) { n = 3; inv = 0x1.555556p-2f; }   // 1/3
    else if (rr == 2) { n = 6; inv = 0x1.555556p-3f; }   // 1/6
    else if (rr == 3) { n = 9; inv = 0x1.c71c72p-4f; }   // 1/9
    else              { n = 0; inv = 0.0f; }

    float d, s = 0.0f;
    d = o0.x - l0.x; s += (0 < n) ? d * d : 0.0f;
    d = o0.y - l0.y; s += (1 < n) ? d * d : 0.0f;
    d = o0.z - l0.z; s += (2 < n) ? d * d : 0.0f;
    d = o0.w - l0.w; s += (3 < n) ? d * d : 0.0f;
    d = o1.x - l1.x; s += (4 < n) ? d * d : 0.0f;
    d = o1.y - l1.y; s += (5 < n) ? d * d : 0.0f;
    d = o1.z - l1.z; s += (6 < n) ? d * d : 0.0f;
    d = o1.w - l1.w; s += (7 < n) ? d * d : 0.0f;
    d = o2.x - l2.x; s += (8 < n) ? d * d : 0.0f;

    return s * inv;
}

__global__ __launch_bounds__(256) void mse2_coop(
    const float4* __restrict__ O4, const float4* __restrict__ L4,
    float* __restrict__ partial, int nrows, float inv_b,
    float* __restrict__ out)
{
    const int tid    = blockIdx.x * blockDim.x + threadIdx.x;
    const int stride = gridDim.x * blockDim.x;

    float acc = 0.0f;

    int r = tid;
    for (; r + stride < nrows; r += 2 * stride) {
        acc += row_term(O4, L4, r);
        acc += row_term(O4, L4, r + stride);
    }
    for (; r < nrows; r += stride)
        acc += row_term(O4, L4, r);

    // wave64 reduction
    #pragma unroll
    for (int off = 32; off >= 1; off >>= 1)
        acc += __shfl_down(acc, off, 64);

    __shared__ float red[4];
    const int wave = threadIdx.x >> 6;
    if ((threadIdx.x & 63) == 0) red[wave] = acc;
    __syncthreads();

    if (threadIdx.x == 0)
        partial[blockIdx.x] = red[0] + red[1] + red[2] + red[3];

    __threadfence();           // make partial visible device-wide
    cg::this_grid().sync();

    if (blockIdx.x == 0) {
        float facc = 0.0f;
        for (int i = threadIdx.x; i < (int)gridDim.x; i += blockDim.x)
            facc += partial[i];

        #pragma unroll
        for (int off = 32; off >= 1; off >>= 1)
            facc += __shfl_down(facc, off, 64);

        __shared__ float fred[4];
        const int wave2 = threadIdx.x >> 6;
        if ((threadIdx.x & 63) == 0) fred[wave2] = facc;
        __syncthreads();

        if (threadIdx.x == 0)
            out[0] = (fred[0] + fred[1] + fred[2] + fred[3]) * inv_b;
    }
}

extern "C" void kernel_launch(void* const* d_in, const int* in_sizes, int n_in,
                              void* d_out, int out_size, void* d_ws, size_t ws_size,
                              hipStream_t stream) {
    const float4* O4 = (const float4*)d_in[0];
    const float4* L4 = (const float4*)d_in[1];

    const int total = in_sizes[0];   // B * 16
    int nrows = total / 16;          // B
    float inv_b = 1.0f / (float)nrows;

    // grid: want 2048 (exact machine fill), clamped to cooperative capacity
    int blocks = 2048;
    int maxPerCU = 0, numCU = 0;
    if (hipOccupancyMaxActiveBlocksPerMultiprocessor(&maxPerCU,
            (const void*)mse2_coop, 256, 0) == hipSuccess &&
        hipDeviceGetAttribute(&numCU, hipDeviceAttributeMultiprocessorCount, 0)
            == hipSuccess && maxPerCU > 0 && numCU > 0) {
        int cap = maxPerCU * numCU;
        if (blocks > cap) blocks = cap;
    }
    int max_blocks = (int)(ws_size / sizeof(float));
    if (max_blocks >= 1 && blocks > max_blocks) blocks = max_blocks;

    float* partial = (float*)d_ws;
    float* outp    = (float*)d_out;

    void* args[] = { (void*)&O4, (void*)&L4, (void*)&partial,
                     (void*)&nrows, (void*)&inv_b, (void*)&outp };
    hipLaunchCooperativeKernel((void*)mse2_coop, dim3(blocks), dim3(256),
                               args, 0, stream);
    (void)n_in; (void)out_size;
}

// Round 6
// 46.298 us; speedup vs baseline: 6.8928x; 6.8928x over previous
//
#include <hip/hip_runtime.h>

// Round 6: revert to R4 verbatim — best measured config (46.35 us).
// Two-kernel structure: lane-per-row main loop (3+3 dwordx4 of each row's
// first 48B, unroll x2 unconditional) + 1-block finale. Fusion alternatives
// both proven regressions: memset-node+atomicAdd = +17us SDMA transition
// (R3), cooperative grid.sync = +273us coherence collapse (R5).
// 268 MB mandatory traffic; kernel1 ~42.5us = 6.31 TB/s = copy ceiling.

__device__ __forceinline__ float row_term(const float4* __restrict__ O4,
                                          const float4* __restrict__ L4,
                                          int r) {
    const int b4 = r * 4;                       // first float4 of row r
    float4 l0 = L4[b4 + 0];
    float4 l1 = L4[b4 + 1];
    float4 l2 = L4[b4 + 2];
    float4 o0 = O4[b4 + 0];
    float4 o1 = O4[b4 + 1];
    float4 o2 = O4[b4 + 2];

    const float lab0 = l0.x;
    const int rr = (int)rintf(3.0f * lab0);     // round-half-even = jnp.round
    int n; float inv;
    if (lab0 == 0.0f) { n = 1; inv = 1.0f; }
    else if (rr == 1) { n = 3; inv = 0x1.555556p-2f; }   // 1/3
    else if (rr == 2) { n = 6; inv = 0x1.555556p-3f; }   // 1/6
    else if (rr == 3) { n = 9; inv = 0x1.c71c72p-4f; }   // 1/9
    else              { n = 0; inv = 0.0f; }

    float d, s = 0.0f;
    d = o0.x - l0.x; s += (0 < n) ? d * d : 0.0f;
    d = o0.y - l0.y; s += (1 < n) ? d * d : 0.0f;
    d = o0.z - l0.z; s += (2 < n) ? d * d : 0.0f;
    d = o0.w - l0.w; s += (3 < n) ? d * d : 0.0f;
    d = o1.x - l1.x; s += (4 < n) ? d * d : 0.0f;
    d = o1.y - l1.y; s += (5 < n) ? d * d : 0.0f;
    d = o1.z - l1.z; s += (6 < n) ? d * d : 0.0f;
    d = o1.w - l1.w; s += (7 < n) ? d * d : 0.0f;
    d = o2.x - l2.x; s += (8 < n) ? d * d : 0.0f;

    return s * inv;
}

__global__ __launch_bounds__(256) void mse2_rows(
    const float4* __restrict__ O4, const float4* __restrict__ L4,
    float* __restrict__ partial, int nrows)
{
    const int tid    = blockIdx.x * blockDim.x + threadIdx.x;
    const int stride = gridDim.x * blockDim.x;

    float acc = 0.0f;

    int r = tid;
    // unroll x2, unconditional bodies (12 independent loads in flight)
    for (; r + stride < nrows; r += 2 * stride) {
        acc += row_term(O4, L4, r);
        acc += row_term(O4, L4, r + stride);
    }
    for (; r < nrows; r += stride)
        acc += row_term(O4, L4, r);

    // wave64 reduction
    #pragma unroll
    for (int off = 32; off >= 1; off >>= 1)
        acc += __shfl_down(acc, off, 64);

    __shared__ float red[4];
    const int wave = threadIdx.x >> 6;
    if ((threadIdx.x & 63) == 0) red[wave] = acc;
    __syncthreads();

    if (threadIdx.x == 0)
        partial[blockIdx.x] = red[0] + red[1] + red[2] + red[3];
}

__global__ __launch_bounds__(256) void mse2_final(
    const float* __restrict__ partial, int nb,
    float* __restrict__ out, float inv_b)
{
    float acc = 0.0f;
    for (int i = threadIdx.x; i < nb; i += blockDim.x)
        acc += partial[i];

    #pragma unroll
    for (int off = 32; off >= 1; off >>= 1)
        acc += __shfl_down(acc, off, 64);

    __shared__ float red[4];
    const int wave = threadIdx.x >> 6;
    if ((threadIdx.x & 63) == 0) red[wave] = acc;
    __syncthreads();

    if (threadIdx.x == 0)
        out[0] = (red[0] + red[1] + red[2] + red[3]) * inv_b;
}

extern "C" void kernel_launch(void* const* d_in, const int* in_sizes, int n_in,
                              void* d_out, int out_size, void* d_ws, size_t ws_size,
                              hipStream_t stream) {
    const float* outputs = (const float*)d_in[0];
    const float* labels  = (const float*)d_in[1];

    const int total = in_sizes[0];   // B * 16
    const int nrows = total / 16;    // B
    const int b     = nrows;

    int threads = 256;
    int blocks  = 2048;
    int max_blocks = (int)(ws_size / sizeof(float));
    if (max_blocks < 1) max_blocks = 1;
    if (blocks > max_blocks) blocks = max_blocks;

    float* partial = (float*)d_ws;

    mse2_rows<<<blocks, threads, 0, stream>>>(
        (const float4*)outputs, (const float4*)labels, partial, nrows);
    mse2_final<<<1, 256, 0, stream>>>(
        partial, blocks, (float*)d_out, 1.0f / (float)b);
    (void)n_in; (void)d_out; (void)out_size;
}